// Round 1
// baseline (344.125 us; speedup 1.0000x reference)
//
#include <hip/hip_runtime.h>
#include <math.h>

// Problem constants (fixed by reference setup_inputs)
constexpr int NB = 8;     // batch
constexpr int NS = 2048;  // sequence
constexpr int ND = 65;    // manifold dim (1 time + 64 space)

// ---------------------------------------------------------------------------
// Kernel 1: per (batch, 64-row block):
//   E[r][t] = exp(-acosh(clip(-<x_r,x_t>_L, 1+1e-7, 50)) / (T+1e-8))
//   rowsum[r] = sum_t E[r][t]   (exact in-block reduction, no atomics)
//   then normalize its own 64x2048 tile in place: attn = E / rowsum
// Scores are always in [-4.61, -4.5e-4] so exp() without max-subtract is safe
// and matches softmax exactly (up to fp rounding).
// ---------------------------------------------------------------------------
__global__ __launch_bounds__(256, 1)
void k1_scores(const float* __restrict__ x, const float* __restrict__ tptr,
               float* __restrict__ attn)
{
    __shared__ float sXr[64][68];    // row tile, time-dim negated, k padded w/ 0
    __shared__ float sXc[128][68];   // col tile
    __shared__ float sInv[64];

    const int tid = threadIdx.x;
    const int b  = blockIdx.y;
    const int r0 = blockIdx.x * 64;
    const int cg = tid & 31;         // column group (32)
    const int rg = tid >> 5;         // row group (8), 8 rows each
    const float invT = 1.0f / (tptr[0] + 1e-8f);

    const float* xb = x + (size_t)b * NS * ND;
    float* arow = attn + ((size_t)b * NS + r0) * NS;   // [64][2048]

    // stage 64 rows, negating the time component so a plain dot = Lorentz product
    for (int i = tid; i < 64 * ND; i += 256) {
        int r = i / ND, d = i - r * ND;
        float v = xb[(size_t)(r0 + r) * ND + d];
        sXr[r][d] = (d == 0) ? -v : v;
    }
    if (tid < 192) sXr[tid / 3][ND + tid % 3] = 0.0f;   // zero-pad k=65..67

    float rsum[8];
    #pragma unroll
    for (int i = 0; i < 8; ++i) rsum[i] = 0.0f;

    for (int tc = 0; tc < NS; tc += 128) {
        __syncthreads();   // protect previous sXc consumers
        for (int i = tid; i < 128 * ND; i += 256) {
            int t = i / ND, d = i - t * ND;
            sXc[t][d] = xb[(size_t)(tc + t) * ND + d];
        }
        for (int i = tid; i < 128 * 3; i += 256)
            sXc[i / 3][ND + i % 3] = 0.0f;
        __syncthreads();

        float acc[8][4];
        #pragma unroll
        for (int i = 0; i < 8; ++i)
            #pragma unroll
            for (int j = 0; j < 4; ++j) acc[i][j] = 0.0f;

        // K-loop, 68 = 17 float4 chunks. Columns interleaved (cg + 32j) to
        // avoid the 32-way bank conflict of consecutive-8-cols-per-thread.
        #pragma unroll 2
        for (int k4 = 0; k4 < 17; ++k4) {
            float4 a[8], c[4];
            #pragma unroll
            for (int i = 0; i < 8; ++i)
                a[i] = *(const float4*)&sXr[rg * 8 + i][k4 * 4];
            #pragma unroll
            for (int j = 0; j < 4; ++j)
                c[j] = *(const float4*)&sXc[cg + 32 * j][k4 * 4];
            #pragma unroll
            for (int i = 0; i < 8; ++i)
                #pragma unroll
                for (int j = 0; j < 4; ++j)
                    acc[i][j] += a[i].x * c[j].x + a[i].y * c[j].y
                               + a[i].z * c[j].z + a[i].w * c[j].w;
        }

        // acosh -> score -> exp, write unnormalized E, accumulate row sums
        #pragma unroll
        for (int i = 0; i < 8; ++i) {
            float rs = 0.0f;
            #pragma unroll
            for (int j = 0; j < 4; ++j) {
                float z = -acc[i][j];                       // acosh input
                z = fminf(fmaxf(z, 1.0000001f), 50.0f);
                float dist = __logf(z + __fsqrt_rn(z * z - 1.0f));
                float e = __expf(-dist * invT);
                arow[(size_t)(rg * 8 + i) * NS + tc + cg + 32 * j] = e;
                rs += e;
            }
            rsum[i] += rs;
        }
    }

    // reduce row sums across the 32 cg lanes (fixed tree -> deterministic)
    #pragma unroll
    for (int i = 0; i < 8; ++i) {
        float v = rsum[i];
        #pragma unroll
        for (int m = 16; m >= 1; m >>= 1) v += __shfl_xor(v, m, 64);
        if (cg == 0) sInv[rg * 8 + i] = 1.0f / v;
    }
    __threadfence_block();
    __syncthreads();

    // normalize this block's 64x2048 tile in place (float4, coalesced, L2-hot)
    float4* af4 = (float4*)arow;
    for (int idx = tid; idx < 64 * (NS / 4); idx += 256) {
        int r = idx >> 9;                 // 512 float4 per row
        float inv = sInv[r];
        float4 v = af4[idx];
        v.x *= inv; v.y *= inv; v.z *= inv; v.w *= inv;
        af4[idx] = v;
    }
}

// ---------------------------------------------------------------------------
// Kernel 2: out[b, r, d] = sum_t attn[b, r, t] * values[b, t, d]
// attn rows streamed from global (L3-resident) into registers as float4;
// V tiles staged in LDS ([128][72] -> conflict-free fragment reads).
// Thread = 4 rows x 4 d-cols (+ shared tail column d=64, stored by cg==15).
// ---------------------------------------------------------------------------
__global__ __launch_bounds__(256, 1)
void k2_pv(const float* __restrict__ attn, const float* __restrict__ values,
           float* __restrict__ out)
{
    __shared__ float sV[128][72];

    const int tid = threadIdx.x;
    const int b  = blockIdx.y;
    const int r0 = blockIdx.x * 64;
    const int cg = tid & 15;     // d group: d = cg*4 .. cg*4+3
    const int rg = tid >> 4;     // 0..15, 4 rows each

    const float* vb = values + (size_t)b * NS * ND;
    const float* arow = attn + ((size_t)b * NS + r0) * NS;

    float acc[4][4];
    float acc64[4];
    #pragma unroll
    for (int i = 0; i < 4; ++i) {
        acc64[i] = 0.0f;
        #pragma unroll
        for (int j = 0; j < 4; ++j) acc[i][j] = 0.0f;
    }

    for (int kt = 0; kt < NS; kt += 128) {
        __syncthreads();
        for (int i = tid; i < 128 * ND; i += 256) {
            int t = i / ND, d = i - t * ND;
            sV[t][d] = vb[(size_t)(kt + t) * ND + d];
        }
        __syncthreads();

        #pragma unroll 2
        for (int k4 = 0; k4 < 32; ++k4) {
            float4 e[4];
            #pragma unroll
            for (int i = 0; i < 4; ++i)
                e[i] = *(const float4*)&arow[(size_t)(rg * 4 + i) * NS + kt + k4 * 4];
            #pragma unroll
            for (int kk = 0; kk < 4; ++kk) {
                float4 vv = *(const float4*)&sV[k4 * 4 + kk][cg * 4];
                float v64 = sV[k4 * 4 + kk][64];
                #pragma unroll
                for (int i = 0; i < 4; ++i) {
                    float ev = (kk == 0) ? e[i].x : (kk == 1) ? e[i].y
                             : (kk == 2) ? e[i].z : e[i].w;
                    acc[i][0] += ev * vv.x;
                    acc[i][1] += ev * vv.y;
                    acc[i][2] += ev * vv.z;
                    acc[i][3] += ev * vv.w;
                    acc64[i]  += ev * v64;
                }
            }
        }
    }

    float* ob = out + ((size_t)b * NS + r0) * ND;
    #pragma unroll
    for (int i = 0; i < 4; ++i) {
        int r = rg * 4 + i;
        #pragma unroll
        for (int j = 0; j < 4; ++j)
            ob[(size_t)r * ND + cg * 4 + j] = acc[i][j];   // 65 stride: scalar stores
        if (cg == 15) ob[(size_t)r * ND + 64] = acc64[i];
    }
}

extern "C" void kernel_launch(void* const* d_in, const int* in_sizes, int n_in,
                              void* d_out, int out_size, void* d_ws, size_t ws_size,
                              hipStream_t stream) {
    const float* x      = (const float*)d_in[0];
    const float* values = (const float*)d_in[1];
    const float* temp   = (const float*)d_in[2];

    float* out  = (float*)d_out;                           // [B,S,D]
    float* attn = out + (size_t)NB * NS * ND;              // [B,S,S]

    dim3 grid(NS / 64, NB);   // 32 x 8 = 256 blocks = 1 per CU
    k1_scores<<<grid, 256, 0, stream>>>(x, temp, attn);
    k2_pv<<<grid, 256, 0, stream>>>(attn, values, out);
}

// Round 2
// 264.862 us; speedup vs baseline: 1.2993x; 1.2993x over previous
//
#include <hip/hip_runtime.h>
#include <math.h>

constexpr int NB = 8;     // batch
constexpr int NS = 2048;  // sequence
constexpr int ND = 65;    // manifold dim (1 time + 64 space)
constexpr size_t OUTSZ = (size_t)NB * NS * ND;   // 1,064,960 floats

// ---------------------------------------------------------------------------
// Kernel 1: per (batch, 64-row block): scores -> E=exp(score) -> rowsum ->
// in-place normalize. 512 threads (8 waves/CU, 2/SIMD) for latency hiding.
// Thread tile 8 rows x 4 cols; cg = tid&63 so each wave = one row-group:
// a-fragment LDS reads are full-wave broadcasts (negligible LDS bytes).
// Scores in [-4.61, -4.5e-4] => exp without max-subtract == softmax exactly.
// ---------------------------------------------------------------------------
__global__ __launch_bounds__(512, 2)
void k1_scores(const float* __restrict__ x, const float* __restrict__ tptr,
               float* __restrict__ attn)
{
    __shared__ float sXr[64][68];    // row tile, time-dim negated, k zero-padded
    __shared__ float sXc[256][68];   // col tile
    __shared__ float sInv[64];

    const int tid = threadIdx.x;
    const int b  = blockIdx.y;
    const int r0 = blockIdx.x * 64;
    const int cg = tid & 63;         // column lane (64) -> cols cg + 64j
    const int rg = tid >> 6;         // wave id == row group (8 rows each)
    const float invT = 1.0f / (tptr[0] + 1e-8f);

    const float* xb = x + (size_t)b * NS * ND;
    float* arow = attn + ((size_t)b * NS + r0) * NS;   // [64][2048]

    for (int i = tid; i < 64 * ND; i += 512) {
        int r = i / ND, d = i - r * ND;
        float v = xb[(size_t)(r0 + r) * ND + d];
        sXr[r][d] = (d == 0) ? -v : v;
    }
    if (tid < 192) sXr[tid / 3][ND + tid % 3] = 0.0f;   // zero-pad k=65..67

    float rsum[8];
    #pragma unroll
    for (int i = 0; i < 8; ++i) rsum[i] = 0.0f;

    for (int tc = 0; tc < NS; tc += 256) {
        __syncthreads();   // protect previous sXc consumers
        for (int i = tid; i < 256 * ND; i += 512) {
            int t = i / ND, d = i - t * ND;
            sXc[t][d] = xb[(size_t)(tc + t) * ND + d];
        }
        for (int i = tid; i < 256 * 3; i += 512)
            sXc[i / 3][ND + i % 3] = 0.0f;
        __syncthreads();

        float acc[8][4];
        #pragma unroll
        for (int i = 0; i < 8; ++i)
            #pragma unroll
            for (int j = 0; j < 4; ++j) acc[i][j] = 0.0f;

        #pragma unroll 2
        for (int k4 = 0; k4 < 17; ++k4) {
            float4 a[8], c[4];
            #pragma unroll
            for (int i = 0; i < 8; ++i)
                a[i] = *(const float4*)&sXr[rg * 8 + i][k4 * 4];   // broadcast
            #pragma unroll
            for (int j = 0; j < 4; ++j)
                c[j] = *(const float4*)&sXc[cg + 64 * j][k4 * 4];
            #pragma unroll
            for (int i = 0; i < 8; ++i)
                #pragma unroll
                for (int j = 0; j < 4; ++j)
                    acc[i][j] += a[i].x * c[j].x + a[i].y * c[j].y
                               + a[i].z * c[j].z + a[i].w * c[j].w;
        }

        #pragma unroll
        for (int i = 0; i < 8; ++i) {
            float rs = 0.0f;
            #pragma unroll
            for (int j = 0; j < 4; ++j) {
                float z = -acc[i][j];
                z = fminf(fmaxf(z, 1.0000001f), 50.0f);
                float dist = __logf(z + __fsqrt_rn(z * z - 1.0f));
                float e = __expf(-dist * invT);
                arow[(size_t)(rg * 8 + i) * NS + tc + cg + 64 * j] = e;
                rs += e;
            }
            rsum[i] += rs;
        }
    }

    // full-wave reduce (each wave owns its 8 rows)
    #pragma unroll
    for (int i = 0; i < 8; ++i) {
        float v = rsum[i];
        #pragma unroll
        for (int m = 32; m >= 1; m >>= 1) v += __shfl_xor(v, m, 64);
        if (cg == 0) sInv[rg * 8 + i] = 1.0f / v;
    }
    __syncthreads();

    float4* af4 = (float4*)arow;
    for (int idx = tid; idx < 64 * (NS / 4); idx += 512) {
        int r = idx >> 9;                 // 512 float4 per row
        float inv = sInv[r];
        float4 v = af4[idx];
        v.x *= inv; v.y *= inv; v.z *= inv; v.w *= inv;
        af4[idx] = v;
    }
}

// ---------------------------------------------------------------------------
// Kernel 2: partial PV over a k-range: dst[b,r,d] (+)= sum_{t in range} attn*V.
// Grid z = k-split => 4 blocks/CU, 16 waves/CU. Thread = 4 rows x 4 d.
// ---------------------------------------------------------------------------
__global__ __launch_bounds__(256, 4)
void k2_pv(const float* __restrict__ attn, const float* __restrict__ values,
           float* __restrict__ dst, int klen)
{
    __shared__ float sV[128][72];

    const int tid = threadIdx.x;
    const int b  = blockIdx.y;
    const int r0 = blockIdx.x * 64;
    const int kt0 = blockIdx.z * klen;
    const int cg = tid & 15;     // d group: d = cg*4 .. cg*4+3
    const int rg = tid >> 4;     // 0..15, 4 rows each

    const float* vb = values + (size_t)b * NS * ND;
    const float* arow = attn + ((size_t)b * NS + r0) * NS;

    float acc[4][4];
    float acc64[4];
    #pragma unroll
    for (int i = 0; i < 4; ++i) {
        acc64[i] = 0.0f;
        #pragma unroll
        for (int j = 0; j < 4; ++j) acc[i][j] = 0.0f;
    }

    for (int kk = 0; kk < klen; kk += 128) {
        const int kt = kt0 + kk;
        __syncthreads();
        for (int i = tid; i < 128 * ND; i += 256) {
            int t = i / ND, d = i - t * ND;
            sV[t][d] = vb[(size_t)(kt + t) * ND + d];
        }
        __syncthreads();

        #pragma unroll 2
        for (int k4 = 0; k4 < 32; ++k4) {
            float4 e[4];
            #pragma unroll
            for (int i = 0; i < 4; ++i)
                e[i] = *(const float4*)&arow[(size_t)(rg * 4 + i) * NS + kt + k4 * 4];
            #pragma unroll
            for (int kx = 0; kx < 4; ++kx) {
                float4 vv = *(const float4*)&sV[k4 * 4 + kx][cg * 4];
                float v64 = sV[k4 * 4 + kx][64];
                #pragma unroll
                for (int i = 0; i < 4; ++i) {
                    float ev = (kx == 0) ? e[i].x : (kx == 1) ? e[i].y
                             : (kx == 2) ? e[i].z : e[i].w;
                    acc[i][0] += ev * vv.x;
                    acc[i][1] += ev * vv.y;
                    acc[i][2] += ev * vv.z;
                    acc[i][3] += ev * vv.w;
                    acc64[i]  += ev * v64;
                }
            }
        }
    }

    // partial for this k-split, laid out like out, offset by blockIdx.z * OUTSZ
    float* ob = dst + (size_t)blockIdx.z * OUTSZ + ((size_t)b * NS + r0) * ND;
    #pragma unroll
    for (int i = 0; i < 4; ++i) {
        int r = rg * 4 + i;
        #pragma unroll
        for (int j = 0; j < 4; ++j)
            ob[(size_t)r * ND + cg * 4 + j] = acc[i][j];
        if (cg == 15) ob[(size_t)r * ND + 64] = acc64[i];
    }
}

// ---------------------------------------------------------------------------
// Kernel 3: out = sum of nsplit partials (deterministic fixed order)
// ---------------------------------------------------------------------------
__global__ __launch_bounds__(256)
void k3_reduce(const float* __restrict__ ws, float* __restrict__ out, int nsplit)
{
    const size_t n4 = OUTSZ / 4;
    size_t i = (size_t)blockIdx.x * 256 + threadIdx.x;
    if (i >= n4) return;
    const float4* w4 = (const float4*)ws;
    float4 s = w4[i];
    for (int sp = 1; sp < nsplit; ++sp) {
        float4 p = w4[i + (size_t)sp * n4];
        s.x += p.x; s.y += p.y; s.z += p.z; s.w += p.w;
    }
    ((float4*)out)[i] = s;
}

extern "C" void kernel_launch(void* const* d_in, const int* in_sizes, int n_in,
                              void* d_out, int out_size, void* d_ws, size_t ws_size,
                              hipStream_t stream) {
    const float* x      = (const float*)d_in[0];
    const float* values = (const float*)d_in[1];
    const float* temp   = (const float*)d_in[2];

    float* out  = (float*)d_out;                           // [B,S,D]
    float* attn = out + OUTSZ;                             // [B,S,S]

    dim3 g1(NS / 64, NB);
    k1_scores<<<g1, 512, 0, stream>>>(x, temp, attn);

    // k-split for occupancy if workspace allows (ws_size fixed => deterministic)
    int ksplit = 1;
    if (ws_size >= 4 * OUTSZ * sizeof(float)) ksplit = 4;
    else if (ws_size >= 2 * OUTSZ * sizeof(float)) ksplit = 2;

    float* dst = (ksplit > 1) ? (float*)d_ws : out;
    dim3 g2(NS / 64, NB, ksplit);
    k2_pv<<<g2, 256, 0, stream>>>(attn, values, dst, NS / ksplit);

    if (ksplit > 1) {
        int nblk = (int)((OUTSZ / 4 + 255) / 256);
        k3_reduce<<<nblk, 256, 0, stream>>>((const float*)d_ws, out, ksplit);
    }
}

// Round 3
// 211.215 us; speedup vs baseline: 1.6293x; 1.2540x over previous
//
#include <hip/hip_runtime.h>
#include <math.h>

constexpr int NB = 8, NS = 2048, ND = 65;
constexpr int KP = 104;                        // padded row stride (bf16 elems): 208B, 16B-aligned, 2-way-free banks
constexpr size_t OUTSZ = (size_t)NB * NS * ND;
constexpr size_t CONVN = (size_t)NB * NS * KP; // elems per converted array

typedef short short8 __attribute__((ext_vector_type(8)));
typedef float f32x4 __attribute__((ext_vector_type(4)));

__device__ __forceinline__ ushort f2bf(float f) {
    uint u = __float_as_uint(f);
    return (ushort)((u + 0x7fffu + ((u >> 16) & 1u)) >> 16);   // RNE
}
__device__ __forceinline__ float bf2f(ushort h) {
    return __uint_as_float((uint)h << 16);
}

// ---------------------------------------------------------------------------
// k0: x fp32 -> (hi, lo) bf16 split arrays, K padded 65->104 with zeros.
// x = hi + lo with |lo| <= 2^-9|x|, lo rounding err 2^-18|x|.
// ---------------------------------------------------------------------------
__global__ __launch_bounds__(256)
void k0_convert(const float* __restrict__ x, ushort* __restrict__ xhi,
                ushort* __restrict__ xlo)
{
    size_t i = (size_t)blockIdx.x * 256 + threadIdx.x;
    if (i >= CONVN) return;
    int d = (int)(i % KP);
    size_t row = i / KP;
    ushort h = 0, l = 0;
    if (d < ND) {
        float v = x[row * ND + d];
        h = f2bf(v);
        l = f2bf(v - bf2f(h));
    }
    xhi[i] = h; xlo[i] = l;
}

// ---------------------------------------------------------------------------
// k1: per (batch, 64-row block): S = Xr(-x0) . Xc^T via split-bf16 MFMA
// (hi*hi + hi*lo + lo*hi), then E=exp(-acosh(clip)/T), rowsum, normalize.
// 512 thr = 8 waves (2x4 wave grid), wave tile 32x64, col tiles of 256.
// mfma_f32_16x16x32_bf16: A/B lane = row/col (lane&15), k = 8*(lane>>4)+e;
// C/D: col=lane&15, row=4*(lane>>4)+reg.
// ---------------------------------------------------------------------------
__global__ __launch_bounds__(512, 1)
void k1_scores(const ushort* __restrict__ xhi, const ushort* __restrict__ xlo,
               const float* __restrict__ tptr, float* __restrict__ attn)
{
    __shared__ __align__(16) ushort sAh[64 * KP], sAl[64 * KP];
    __shared__ __align__(16) ushort sBh[256 * KP], sBl[256 * KP];
    __shared__ float sSum[4][64];
    __shared__ float sInv[64];

    const int tid = threadIdx.x;
    const int b  = blockIdx.y;
    const int r0 = blockIdx.x * 64;
    const int lane = tid & 63;
    const int w  = tid >> 6;
    const int wr = w >> 2;          // 0..1  (32-row slab)
    const int wc = w & 3;           // 0..3  (64-col slab)
    const float invT = 1.0f / (tptr[0] + 1e-8f);

    const ushort* xhb = xhi + (size_t)b * NS * KP;
    const ushort* xlb = xlo + (size_t)b * NS * KP;
    float* arow = attn + ((size_t)b * NS + r0) * NS;

    // stage A rows (64 x KP, hi+lo) -- contiguous copy
    {
        const uint4* sh = (const uint4*)(xhb + (size_t)r0 * KP);
        const uint4* sl = (const uint4*)(xlb + (size_t)r0 * KP);
        uint4* dh = (uint4*)sAh; uint4* dl = (uint4*)sAl;
        for (int i = tid; i < 64 * KP / 8; i += 512) { dh[i] = sh[i]; dl[i] = sl[i]; }
    }
    __syncthreads();
    if (tid < 64) { sAh[tid * KP] ^= 0x8000; sAl[tid * KP] ^= 0x8000; }  // Lorentz: negate time dim in rows

    float rsum[2][4];
    #pragma unroll
    for (int rf = 0; rf < 2; ++rf)
        #pragma unroll
        for (int j = 0; j < 4; ++j) rsum[rf][j] = 0.0f;

    for (int tc = 0; tc < NS; tc += 256) {
        __syncthreads();
        {
            const uint4* sh = (const uint4*)(xhb + (size_t)tc * KP);
            const uint4* sl = (const uint4*)(xlb + (size_t)tc * KP);
            uint4* dh = (uint4*)sBh; uint4* dl = (uint4*)sBl;
            for (int i = tid; i < 256 * KP / 8; i += 512) { dh[i] = sh[i]; dl[i] = sl[i]; }
        }
        __syncthreads();

        f32x4 acc[2][4];
        #pragma unroll
        for (int rf = 0; rf < 2; ++rf)
            #pragma unroll
            for (int cf = 0; cf < 4; ++cf)
                #pragma unroll
                for (int j = 0; j < 4; ++j) acc[rf][cf][j] = 0.0f;

        #pragma unroll
        for (int kc = 0; kc < 3; ++kc) {
            const int koff = kc * 32 + (lane >> 4) * 8;
            short8 ah[2], al[2], bh[4], bl[4];
            #pragma unroll
            for (int rf = 0; rf < 2; ++rf) {
                int ro = (wr * 32 + rf * 16 + (lane & 15)) * KP + koff;
                ah[rf] = *(const short8*)&sAh[ro];
                al[rf] = *(const short8*)&sAl[ro];
            }
            #pragma unroll
            for (int cf = 0; cf < 4; ++cf) {
                int co = (wc * 64 + cf * 16 + (lane & 15)) * KP + koff;
                bh[cf] = *(const short8*)&sBh[co];
                bl[cf] = *(const short8*)&sBl[co];
            }
            #pragma unroll
            for (int rf = 0; rf < 2; ++rf)
                #pragma unroll
                for (int cf = 0; cf < 4; ++cf) {
                    acc[rf][cf] = __builtin_amdgcn_mfma_f32_16x16x32_bf16(ah[rf], bh[cf], acc[rf][cf], 0, 0, 0);
                    acc[rf][cf] = __builtin_amdgcn_mfma_f32_16x16x32_bf16(ah[rf], bl[cf], acc[rf][cf], 0, 0, 0);
                    acc[rf][cf] = __builtin_amdgcn_mfma_f32_16x16x32_bf16(al[rf], bh[cf], acc[rf][cf], 0, 0, 0);
                }
        }

        // epilogue: acosh -> exp, write E, accumulate row sums
        #pragma unroll
        for (int rf = 0; rf < 2; ++rf)
            #pragma unroll
            for (int cf = 0; cf < 4; ++cf)
                #pragma unroll
                for (int j = 0; j < 4; ++j) {
                    float z = -acc[rf][cf][j];
                    z = fminf(fmaxf(z, 1.0000001f), 50.0f);
                    float dist = __logf(z + __fsqrt_rn(z * z - 1.0f));
                    float e = __expf(-dist * invT);
                    int row = wr * 32 + rf * 16 + (lane >> 4) * 4 + j;
                    int col = tc + wc * 64 + cf * 16 + (lane & 15);
                    arow[(size_t)row * NS + col] = e;
                    rsum[rf][j] += e;
                }
    }

    // deterministic row-sum reduce: 16 lanes (lane&15) share each row
    #pragma unroll
    for (int rf = 0; rf < 2; ++rf)
        #pragma unroll
        for (int j = 0; j < 4; ++j) {
            float v = rsum[rf][j];
            v += __shfl_xor(v, 1, 64);
            v += __shfl_xor(v, 2, 64);
            v += __shfl_xor(v, 4, 64);
            v += __shfl_xor(v, 8, 64);
            if ((lane & 15) == 0)
                sSum[wc][wr * 32 + rf * 16 + (lane >> 4) * 4 + j] = v;
        }
    __syncthreads();
    if (tid < 64)
        sInv[tid] = 1.0f / (sSum[0][tid] + sSum[1][tid] + sSum[2][tid] + sSum[3][tid]);
    __syncthreads();

    // normalize this block's 64x2048 tile in place (L2-hot)
    float4* af4 = (float4*)arow;
    for (int idx = tid; idx < 64 * (NS / 4); idx += 512) {
        int r = idx >> 9;
        float inv = sInv[r];
        float4 v = af4[idx];
        v.x *= inv; v.y *= inv; v.z *= inv; v.w *= inv;
        af4[idx] = v;
    }
}

// ---------------------------------------------------------------------------
// k2: partial PV over a k-range (unchanged from r2)
// ---------------------------------------------------------------------------
__global__ __launch_bounds__(256, 4)
void k2_pv(const float* __restrict__ attn, const float* __restrict__ values,
           float* __restrict__ dst, int klen)
{
    __shared__ float sV[128][72];

    const int tid = threadIdx.x;
    const int b  = blockIdx.y;
    const int r0 = blockIdx.x * 64;
    const int kt0 = blockIdx.z * klen;
    const int cg = tid & 15;
    const int rg = tid >> 4;

    const float* vb = values + (size_t)b * NS * ND;
    const float* arow = attn + ((size_t)b * NS + r0) * NS;

    float acc[4][4];
    float acc64[4];
    #pragma unroll
    for (int i = 0; i < 4; ++i) {
        acc64[i] = 0.0f;
        #pragma unroll
        for (int j = 0; j < 4; ++j) acc[i][j] = 0.0f;
    }

    for (int kk = 0; kk < klen; kk += 128) {
        const int kt = kt0 + kk;
        __syncthreads();
        for (int i = tid; i < 128 * ND; i += 256) {
            int t = i / ND, d = i - t * ND;
            sV[t][d] = vb[(size_t)(kt + t) * ND + d];
        }
        __syncthreads();

        #pragma unroll 2
        for (int k4 = 0; k4 < 32; ++k4) {
            float4 e[4];
            #pragma unroll
            for (int i = 0; i < 4; ++i)
                e[i] = *(const float4*)&arow[(size_t)(rg * 4 + i) * NS + kt + k4 * 4];
            #pragma unroll
            for (int kx = 0; kx < 4; ++kx) {
                float4 vv = *(const float4*)&sV[k4 * 4 + kx][cg * 4];
                float v64 = sV[k4 * 4 + kx][64];
                #pragma unroll
                for (int i = 0; i < 4; ++i) {
                    float ev = (kx == 0) ? e[i].x : (kx == 1) ? e[i].y
                             : (kx == 2) ? e[i].z : e[i].w;
                    acc[i][0] += ev * vv.x;
                    acc[i][1] += ev * vv.y;
                    acc[i][2] += ev * vv.z;
                    acc[i][3] += ev * vv.w;
                    acc64[i]  += ev * v64;
                }
            }
        }
    }

    float* ob = dst + (size_t)blockIdx.z * OUTSZ + ((size_t)b * NS + r0) * ND;
    #pragma unroll
    for (int i = 0; i < 4; ++i) {
        int r = rg * 4 + i;
        #pragma unroll
        for (int j = 0; j < 4; ++j)
            ob[(size_t)r * ND + cg * 4 + j] = acc[i][j];
        if (cg == 15) ob[(size_t)r * ND + 64] = acc64[i];
    }
}

__global__ __launch_bounds__(256)
void k3_reduce(const float* __restrict__ ws, float* __restrict__ out, int nsplit)
{
    const size_t n4 = OUTSZ / 4;
    size_t i = (size_t)blockIdx.x * 256 + threadIdx.x;
    if (i >= n4) return;
    const float4* w4 = (const float4*)ws;
    float4 s = w4[i];
    for (int sp = 1; sp < nsplit; ++sp) {
        float4 p = w4[i + (size_t)sp * n4];
        s.x += p.x; s.y += p.y; s.z += p.z; s.w += p.w;
    }
    ((float4*)out)[i] = s;
}

extern "C" void kernel_launch(void* const* d_in, const int* in_sizes, int n_in,
                              void* d_out, int out_size, void* d_ws, size_t ws_size,
                              hipStream_t stream) {
    const float* x      = (const float*)d_in[0];
    const float* values = (const float*)d_in[1];
    const float* temp   = (const float*)d_in[2];

    float* out  = (float*)d_out;
    float* attn = out + OUTSZ;

    // conversion buffers live at ws[0]; k2's partials later clobber them
    // (k0 rewrites every call -> deterministic)
    ushort* xhi = (ushort*)d_ws;
    ushort* xlo = xhi + CONVN;

    k0_convert<<<(int)((CONVN + 255) / 256), 256, 0, stream>>>(x, xhi, xlo);

    dim3 g1(NS / 64, NB);
    k1_scores<<<g1, 512, 0, stream>>>(xhi, xlo, temp, attn);

    int ksplit = 1;
    if (ws_size >= 4 * OUTSZ * sizeof(float)) ksplit = 4;
    else if (ws_size >= 2 * OUTSZ * sizeof(float)) ksplit = 2;

    float* dst = (ksplit > 1) ? (float*)d_ws : out;
    dim3 g2(NS / 64, NB, ksplit);
    k2_pv<<<g2, 256, 0, stream>>>(attn, values, dst, NS / ksplit);

    if (ksplit > 1) {
        int nblk = (int)((OUTSZ / 4 + 255) / 256);
        k3_reduce<<<nblk, 256, 0, stream>>>((const float*)d_ws, out, ksplit);
    }
}

// Round 4
// 165.095 us; speedup vs baseline: 2.0844x; 1.2794x over previous
//
#include <hip/hip_runtime.h>
#include <math.h>

constexpr int NB = 8, NS = 2048, ND = 65;
constexpr int KP = 104;     // padded K stride for x conv (bf16 elems)
constexpr int VD = 80;      // padded d rows for V^T
constexpr size_t OUTSZ = (size_t)NB * NS * ND;
constexpr size_t CONVN = (size_t)NB * NS * KP;   // x conv elems per array
constexpr size_t VTN   = (size_t)NB * VD * NS;   // V^T elems per array

typedef short short8 __attribute__((ext_vector_type(8)));
typedef float f32x4 __attribute__((ext_vector_type(4)));

__device__ __forceinline__ ushort f2bf(float f) {
    uint u = __float_as_uint(f);
    return (ushort)((u + 0x7fffu + ((u >> 16) & 1u)) >> 16);   // RNE
}
__device__ __forceinline__ float bf2f(ushort h) {
    return __uint_as_float((uint)h << 16);
}

// ---------------------------------------------------------------------------
// k0x: x fp32 -> (hi, lo) bf16 split arrays, K padded 65->104 with zeros.
// ---------------------------------------------------------------------------
__global__ __launch_bounds__(256)
void k0_convert(const float* __restrict__ x, ushort* __restrict__ xhi,
                ushort* __restrict__ xlo)
{
    size_t i = (size_t)blockIdx.x * 256 + threadIdx.x;
    if (i >= CONVN) return;
    int d = (int)(i % KP);
    size_t row = i / KP;
    ushort h = 0, l = 0;
    if (d < ND) {
        float v = x[row * ND + d];
        h = f2bf(v);
        l = f2bf(v - bf2f(h));
    }
    xhi[i] = h; xlo[i] = l;
}

// ---------------------------------------------------------------------------
// k0v: V [b,t,d] fp32 -> V^T hi/lo bf16 [b, d(80, zero-pad), t(2048)]
// LDS tile transpose: coalesced read over (t,d), coalesced write over t.
// ---------------------------------------------------------------------------
__global__ __launch_bounds__(256)
void k0v_transpose(const float* __restrict__ v, ushort* __restrict__ vthi,
                   ushort* __restrict__ vtlo)
{
    __shared__ float sT[128][66];
    const int tid = threadIdx.x, b = blockIdx.y, t0 = blockIdx.x * 128;
    const float* vb = v + (size_t)b * NS * ND;
    for (int i = tid; i < 128 * ND; i += 256) {
        int t = i / ND, d = i - t * ND;
        sT[t][d] = vb[(size_t)(t0 + t) * ND + d];
    }
    __syncthreads();
    for (int i = tid; i < VD * 128; i += 256) {
        int d = i >> 7, t = i & 127;
        float val = (d < ND) ? sT[t][d] : 0.0f;
        ushort h = f2bf(val);
        ushort l = f2bf(val - bf2f(h));
        size_t o = ((size_t)b * VD + d) * NS + t0 + t;
        vthi[o] = h; vtlo[o] = l;
    }
}

// ---------------------------------------------------------------------------
// k1: per (batch, 64-row block): S via split-bf16 MFMA (hi*hi+hi*lo+lo*hi),
// E = exp(-acosh(clip)/T) written fp32 (NO normalize pass), inv[row] -> ws.
// Scores in [-4.61, -4.5e-4] => exp without max-subtract == softmax exactly.
// ---------------------------------------------------------------------------
__global__ __launch_bounds__(512, 1)
void k1_scores(const ushort* __restrict__ xhi, const ushort* __restrict__ xlo,
               const float* __restrict__ tptr, float* __restrict__ attn,
               float* __restrict__ invb)
{
    __shared__ __align__(16) ushort sAh[64 * KP], sAl[64 * KP];
    __shared__ __align__(16) ushort sBh[256 * KP], sBl[256 * KP];
    __shared__ float sSum[4][64];

    const int tid = threadIdx.x;
    const int b  = blockIdx.y;
    const int r0 = blockIdx.x * 64;
    const int lane = tid & 63;
    const int w  = tid >> 6;
    const int wr = w >> 2;          // 0..1  (32-row slab)
    const int wc = w & 3;           // 0..3  (64-col slab)
    const float invT = 1.0f / (tptr[0] + 1e-8f);

    const ushort* xhb = xhi + (size_t)b * NS * KP;
    const ushort* xlb = xlo + (size_t)b * NS * KP;
    float* arow = attn + ((size_t)b * NS + r0) * NS;

    {
        const uint4* sh = (const uint4*)(xhb + (size_t)r0 * KP);
        const uint4* sl = (const uint4*)(xlb + (size_t)r0 * KP);
        uint4* dh = (uint4*)sAh; uint4* dl = (uint4*)sAl;
        for (int i = tid; i < 64 * KP / 8; i += 512) { dh[i] = sh[i]; dl[i] = sl[i]; }
    }
    __syncthreads();
    if (tid < 64) { sAh[tid * KP] ^= 0x8000; sAl[tid * KP] ^= 0x8000; }  // negate time dim

    float rsum[2][4];
    #pragma unroll
    for (int rf = 0; rf < 2; ++rf)
        #pragma unroll
        for (int j = 0; j < 4; ++j) rsum[rf][j] = 0.0f;

    for (int tc = 0; tc < NS; tc += 256) {
        __syncthreads();
        {
            const uint4* sh = (const uint4*)(xhb + (size_t)tc * KP);
            const uint4* sl = (const uint4*)(xlb + (size_t)tc * KP);
            uint4* dh = (uint4*)sBh; uint4* dl = (uint4*)sBl;
            for (int i = tid; i < 256 * KP / 8; i += 512) { dh[i] = sh[i]; dl[i] = sl[i]; }
        }
        __syncthreads();

        f32x4 acc[2][4];
        #pragma unroll
        for (int rf = 0; rf < 2; ++rf)
            #pragma unroll
            for (int cf = 0; cf < 4; ++cf)
                #pragma unroll
                for (int j = 0; j < 4; ++j) acc[rf][cf][j] = 0.0f;

        #pragma unroll
        for (int kc = 0; kc < 3; ++kc) {
            const int koff = kc * 32 + (lane >> 4) * 8;
            short8 ah[2], al[2], bh[4], bl[4];
            #pragma unroll
            for (int rf = 0; rf < 2; ++rf) {
                int ro = (wr * 32 + rf * 16 + (lane & 15)) * KP + koff;
                ah[rf] = *(const short8*)&sAh[ro];
                al[rf] = *(const short8*)&sAl[ro];
            }
            #pragma unroll
            for (int cf = 0; cf < 4; ++cf) {
                int co = (wc * 64 + cf * 16 + (lane & 15)) * KP + koff;
                bh[cf] = *(const short8*)&sBh[co];
                bl[cf] = *(const short8*)&sBl[co];
            }
            #pragma unroll
            for (int rf = 0; rf < 2; ++rf)
                #pragma unroll
                for (int cf = 0; cf < 4; ++cf) {
                    acc[rf][cf] = __builtin_amdgcn_mfma_f32_16x16x32_bf16(ah[rf], bh[cf], acc[rf][cf], 0, 0, 0);
                    acc[rf][cf] = __builtin_amdgcn_mfma_f32_16x16x32_bf16(ah[rf], bl[cf], acc[rf][cf], 0, 0, 0);
                    acc[rf][cf] = __builtin_amdgcn_mfma_f32_16x16x32_bf16(al[rf], bh[cf], acc[rf][cf], 0, 0, 0);
                }
        }

        #pragma unroll
        for (int rf = 0; rf < 2; ++rf)
            #pragma unroll
            for (int cf = 0; cf < 4; ++cf)
                #pragma unroll
                for (int j = 0; j < 4; ++j) {
                    float z = -acc[rf][cf][j];
                    z = fminf(fmaxf(z, 1.0000001f), 50.0f);
                    float dist = __logf(z + __fsqrt_rn(z * z - 1.0f));
                    float e = __expf(-dist * invT);
                    int row = wr * 32 + rf * 16 + (lane >> 4) * 4 + j;
                    int col = tc + wc * 64 + cf * 16 + (lane & 15);
                    arow[(size_t)row * NS + col] = e;
                    rsum[rf][j] += e;
                }
    }

    // deterministic row-sum reduce: 16 lanes (lane&15) share each row
    #pragma unroll
    for (int rf = 0; rf < 2; ++rf)
        #pragma unroll
        for (int j = 0; j < 4; ++j) {
            float v = rsum[rf][j];
            v += __shfl_xor(v, 1, 64);
            v += __shfl_xor(v, 2, 64);
            v += __shfl_xor(v, 4, 64);
            v += __shfl_xor(v, 8, 64);
            if ((lane & 15) == 0)
                sSum[wc][wr * 32 + rf * 16 + (lane >> 4) * 4 + j] = v;
        }
    __syncthreads();
    if (tid < 64)
        invb[(size_t)b * NS + r0 + tid] =
            1.0f / (sSum[0][tid] + sSum[1][tid] + sSum[2][tid] + sSum[3][tid]);
}

// ---------------------------------------------------------------------------
// k2: per (batch, 16-row block): read E tile (L3-hot), normalize, write attn
// back in place, split to bf16 hi/lo in LDS; MFMA PV with B = V^T hi/lo read
// straight from global (L2-hot). 4 waves k-slice the 128-chunk; LDS reduce.
// ---------------------------------------------------------------------------
__global__ __launch_bounds__(256, 4)
void k2_pv(float* __restrict__ attn, const ushort* __restrict__ vthi,
           const ushort* __restrict__ vtlo, const float* __restrict__ invb,
           float* __restrict__ out)
{
    __shared__ __align__(16) ushort sAh[16 * 136], sAl[16 * 136];
    __shared__ float sRed[4][16][VD];
    __shared__ float sInvL[16];

    const int tid = threadIdx.x;
    const int b  = blockIdx.y;
    const int r0 = blockIdx.x * 16;
    const int lane = tid & 63;
    const int wk = tid >> 6;          // k-slice 0..3 within each 128-chunk

    if (tid < 16) sInvL[tid] = invb[(size_t)b * NS + r0 + tid];

    float* arow = attn + ((size_t)b * NS + r0) * NS;
    const ushort* vh = vthi + (size_t)b * VD * NS;
    const ushort* vl = vtlo + (size_t)b * VD * NS;

    f32x4 acc[5];
    #pragma unroll
    for (int f = 0; f < 5; ++f)
        #pragma unroll
        for (int j = 0; j < 4; ++j) acc[f][j] = 0.0f;

    __syncthreads();

    for (int kt = 0; kt < NS; kt += 128) {
        // stage 16x128: read E, normalize, write attn, bf16-split into LDS
        #pragma unroll
        for (int rep = 0; rep < 2; ++rep) {
            int idx = tid + rep * 256;          // 512 float4 = 16 rows x 32
            int row = idx >> 5, c4 = idx & 31;
            float4* p = (float4*)&arow[(size_t)row * NS + kt + c4 * 4];
            float4 e = *p;
            float inv = sInvL[row];
            e.x *= inv; e.y *= inv; e.z *= inv; e.w *= inv;
            *p = e;
            ushort h0 = f2bf(e.x), h1 = f2bf(e.y), h2 = f2bf(e.z), h3 = f2bf(e.w);
            ushort l0 = f2bf(e.x - bf2f(h0)), l1 = f2bf(e.y - bf2f(h1));
            ushort l2 = f2bf(e.z - bf2f(h2)), l3 = f2bf(e.w - bf2f(h3));
            int so = row * 136 + c4 * 4;
            *(ushort4*)&sAh[so] = make_ushort4(h0, h1, h2, h3);
            *(ushort4*)&sAl[so] = make_ushort4(l0, l1, l2, l3);
        }
        __syncthreads();

        const int koff = wk * 32 + (lane >> 4) * 8;
        short8 ah = *(const short8*)&sAh[(lane & 15) * 136 + koff];
        short8 al = *(const short8*)&sAl[(lane & 15) * 136 + koff];
        #pragma unroll
        for (int f = 0; f < 5; ++f) {
            size_t vo = (size_t)(f * 16 + (lane & 15)) * NS + kt + koff;
            short8 bh = *(const short8*)&vh[vo];
            short8 bl = *(const short8*)&vl[vo];
            acc[f] = __builtin_amdgcn_mfma_f32_16x16x32_bf16(ah, bh, acc[f], 0, 0, 0);
            acc[f] = __builtin_amdgcn_mfma_f32_16x16x32_bf16(ah, bl, acc[f], 0, 0, 0);
            acc[f] = __builtin_amdgcn_mfma_f32_16x16x32_bf16(al, bh, acc[f], 0, 0, 0);
        }
        __syncthreads();   // protect sA rewrite next chunk
    }

    // cross-wave reduce of the 4 k-slices
    #pragma unroll
    for (int f = 0; f < 5; ++f)
        #pragma unroll
        for (int j = 0; j < 4; ++j)
            sRed[wk][(lane >> 4) * 4 + j][f * 16 + (lane & 15)] = acc[f][j];
    __syncthreads();
    for (int i = tid; i < 16 * VD; i += 256) {
        int r = i / VD, d = i - r * VD;
        float s = sRed[0][r][d] + sRed[1][r][d] + sRed[2][r][d] + sRed[3][r][d];
        if (d < ND) out[((size_t)b * NS + r0 + r) * ND + d] = s;
    }
}

extern "C" void kernel_launch(void* const* d_in, const int* in_sizes, int n_in,
                              void* d_out, int out_size, void* d_ws, size_t ws_size,
                              hipStream_t stream) {
    const float* x      = (const float*)d_in[0];
    const float* values = (const float*)d_in[1];
    const float* temp   = (const float*)d_in[2];

    float* out  = (float*)d_out;
    float* attn = out + OUTSZ;

    // ws layout (12.2 MB total; ws proven >= 17 MB in round 2/3):
    ushort* xhi  = (ushort*)d_ws;
    ushort* xlo  = xhi + CONVN;
    ushort* vthi = xlo + CONVN;
    ushort* vtlo = vthi + VTN;
    float*  invb = (float*)(vtlo + VTN);

    k0_convert<<<(int)((CONVN + 255) / 256), 256, 0, stream>>>(x, xhi, xlo);
    k0v_transpose<<<dim3(NS / 128, NB), 256, 0, stream>>>(values, vthi, vtlo);

    k1_scores<<<dim3(NS / 64, NB), 512, 0, stream>>>(xhi, xlo, temp, attn, invb);
    k2_pv<<<dim3(NS / 16, NB), 256, 0, stream>>>(attn, vthi, vtlo, invb, out);
}